// Round 3
// baseline (190.070 us; speedup 1.0000x reference)
//
#include <hip/hip_runtime.h>
#include <hip/hip_bf16.h>
#include <math.h>

// PillarHist: per-row 64-bin hist (count/mean_z/mean_r interleaved) -> Linear(192->64) -> BN(train) -> ReLU
// k0 (16 blocks): build permuted bf16 B-fragments into d_ws + zero BN totals (16 replicas).
// k1 (1563 blocks, 128 threads = ONE wave pair, 4 tiles x 16 rows = 64 rows/block):
//     PIPELINED tiles: B-fragments loaded ONCE per wave (12 frags, 48 VGPRs); tile t+1's
//     zw/nump loads issued before tile t's hist+decode (double-buffered registers); hist strips
//     double-buffered in LDS (2 x 16 x 66 u64 = 16.9 KB) -> ONE pair-exact __syncthreads/tile.
//     u64-packed hist: ONE ds_add_u64 per point (hi = count<<24 | biased z, lo = biased r).
//     MFMA by bin-group: 4 contiguous ds_read_b128 deliver z+r for 8 bins; count/mean_z/mean_r
//     substages run from registers. BN partials accumulate across tiles -> 2 atomics/wave total.
// k3: sum replicas -> scale/shift -> apply BN+ReLU in-place (grid-stride).

typedef __attribute__((ext_vector_type(8))) short bf16x8;   // 8 bf16 = 4 VGPRs = 16 B
typedef __attribute__((ext_vector_type(4))) float f32x4;
typedef __attribute__((ext_vector_type(4))) int   i32x4;

#define ZMINF   (-3.0f)
#define INV_BIN 16.0f            // 1/BIN_SIZE (exact pow2)
#define QS      8192.0f          // 2^13 payload scale
#define INV_QS  (1.0f / 8192.0f)
#define PBIASF  65536.0f         // 2^16 payload bias (covers |z|<8; 64*max_payload < 2^24)
#define PBIASI  65536
#define CBIT    16777216         // 2^24 count increment (hi word only)
#define TSC     16777216.0f     // 2^24 fixed-point scale for BN totals
#define INV_TSC (1.0f / 16777216.0f)
#define REPS    16               // BN total replicas
#define RSTRIDE 66               // u64 per row (64 bins + 2 pad -> 2-way-max read bank profile)
#define TILES   4                // 16-row tiles per block

__device__ __forceinline__ short f2bf(float f) {
    __hip_bfloat16 h = __float2bfloat16(f);   // RNE
    return __builtin_bit_cast(short, h);
}

// ---- k0: grid-stride. Permuted W -> bf16 fragments (frag-major [s*4+t][lane][j]) + zero totals ----
__global__ __launch_bounds__(256)
void k0_prep(const float* __restrict__ W,                  // [64,192]
             short*       __restrict__ wsW,                // [24*64*8] bf16
             unsigned long long* __restrict__ totals)      // [REPS*128]
{
    const int tid    = blockIdx.x * 256 + threadIdx.x;
    const int stride = gridDim.x * 256;
    for (int e = tid; e < 24 * 64 * 8; e += stride) {
        const int j  = e & 7;
        const int ln = (e >> 3) & 63;
        const int st = e >> 9;                       // s*4+t
        const int s  = st >> 2, t = st & 3;
        const int k  = s * 32 + (ln >> 4) * 8 + j;   // planar k
        const int n  = t * 16 + (ln & 15);           // output channel
        const int wc = (k < 64) ? 3 * k
                     : (k < 128) ? 3 * (k - 64) + 1
                                 : 3 * (k - 128) + 2;
        wsW[e] = f2bf(W[n * 192 + wc]);
    }
    for (int e = tid; e < REPS * 128; e += stride) totals[e] = 0ull;
}

__global__ __launch_bounds__(128, 3)
void k1_hist_mfma(const uint2*  __restrict__ feat2,  // feat as uint2; zw of (row,pt) at (row*64+pt)*2+1
                  const int*    __restrict__ nump,   // [M]
                  const bf16x8* __restrict__ wsWf,   // [24*64] B fragments (global, L2-hot)
                  const float*  __restrict__ bvec,   // [64]
                  float*        __restrict__ xout,   // [M,64] pre-BN x (d_out)
                  unsigned long long* __restrict__ totals, // [REPS*128] fixed-point sum | sumsq
                  int M)
{
    __shared__ unsigned long long sH[2][16 * RSTRIDE];   // 16896 B: double-buffered hist strips

    const int tid  = threadIdx.x;
    const int half = tid >> 6;          // 0,1 — one pair per block; output half t in {2h,2h+1}
    const int lane = tid & 63;
    const int col  = lane & 15;
    const int quad = lane >> 4;

    const int gbase0 = blockIdx.x * (16 * TILES);

    // ---- B fragments loaded ONCE per wave: plane p (0..5), tt (0..1) ----
    bf16x8 bfr[6][2];
    #pragma unroll
    for (int p = 0; p < 6; ++p) {
        #pragma unroll
        for (int tt = 0; tt < 2; ++tt)
            bfr[p][tt] = wsWf[(p * 4 + half * 2 + tt) * 64 + lane];
    }

    float psum[2] = {0.f, 0.f};
    float psq[2]  = {0.f, 0.f};

    uint2 zw[2][8];     // double-buffered row loads (compile-time indexed: t-loop unrolled)
    int   npv[2];

    // ---- prologue: prefetch tile 0 ----
    {
        npv[0] = nump[min(gbase0 + half * 8 + (lane & 7), M - 1)];
        #pragma unroll
        for (int uu = 0; uu < 8; ++uu) {
            const int rc = min(gbase0 + half * 8 + uu, M - 1);
            zw[0][uu] = feat2[((size_t)rc * 64 + lane) * 2 + 1];
        }
    }

    #pragma unroll
    for (int t = 0; t < TILES; ++t) {
        const int gbase = gbase0 + t * 16;
        if (gbase < M) {                      // block-uniform: barrier inside is safe
            const int cur = t & 1;
            const int nxt = cur ^ 1;

            // ---- prefetch tile t+1 (independent regs; latency hides under hist+decode) ----
            if (t + 1 < TILES) {
                const int gb = gbase0 + (t + 1) * 16;
                npv[nxt] = nump[min(gb + half * 8 + (lane & 7), M - 1)];
                #pragma unroll
                for (int uu = 0; uu < 8; ++uu) {
                    const int rc = min(gb + half * 8 + uu, M - 1);
                    zw[nxt][uu] = feat2[((size_t)rc * 64 + lane) * 2 + 1];
                }
            }

            // ---- zero OWN 8-row bin region of strip[cur] (4096 B, 4 unguarded b128 rounds;
            //      pad words never read, left dirty) ----
            {
                int* base = (int*)&sH[cur][0];
                #pragma unroll
                for (int i = 0; i < 4; ++i) {
                    const int idx = lane + i * 64;                  // 0..255
                    const int off = (half * 8 + (idx >> 5)) * (RSTRIDE * 2) + (idx & 31) * 4;
                    *(i32x4*)(base + off) = i32x4{0, 0, 0, 0};
                }
            }
            __builtin_amdgcn_wave_barrier();

            // ---- packed hist, own 8 rows: ONE native ds_add_u64 per point ----
            #pragma unroll
            for (int uu = 0; uu < 8; ++uu) {
                const int u = half * 8 + uu;
                int np_u = __builtin_amdgcn_readlane(npv[cur], uu);
                np_u = (gbase + u < M) ? np_u : 0;                   // uniform tail guard
                if (lane < np_u) {
                    const float z  = __int_as_float((int)zw[cur][uu].x);
                    const float rr = __int_as_float((int)zw[cur][uu].y);
                    int bi = (int)((z - ZMINF) * INV_BIN);           // trunc, matches astype(int32)
                    bi = min(max(bi, 0), 63);
                    const unsigned long long add =
                        ((unsigned long long)(unsigned)(CBIT + PBIASI + (int)(z * QS)) << 32)
                        | (unsigned)(PBIASI + (int)(rr * QS));
                    atomicAdd(&sH[cur][u * RSTRIDE + bi], add);
                }
            }

            __syncthreads();   // pair-exact: partner's 8 rows complete & visible;
                               // also orders next iteration's zero vs partner's reads of buf nxt

            // ---- MFMA: A rows = col; bin-group g covers bins g*32+quad*8..+7 ----
            f32x4 acc[2] = {};
            const int* ar = (const int*)&sH[cur][0] + col * (RSTRIDE * 2);
            #pragma unroll
            for (int g = 0; g < 2; ++g) {
                const int o0 = g * 32 + quad * 8;               // first bin of this lane's slice
                const i32x4* ap = (const i32x4*)(ar + 2 * o0);  // 64 B contiguous: 8 bins (r,z)x4
                const i32x4 a0 = ap[0], a1 = ap[1], a2 = ap[2], a3 = ap[3];
                const int zz[8]  = {a0.y, a0.w, a1.y, a1.w, a2.y, a2.w, a3.y, a3.w};
                const int rrw[8] = {a0.x, a0.z, a1.x, a1.z, a2.x, a2.z, a3.x, a3.z};
                float cnt[8], rcp[8], av[8];
                bf16x8 af;

                // -- substage A: counts (plane g) --
                #pragma unroll
                for (int j = 0; j < 8; ++j) { cnt[j] = (float)(zz[j] >> 24); av[j] = cnt[j]; }
                #pragma unroll
                for (int j = 0; j < 8; ++j) af[j] = f2bf(av[j]);
                acc[0] = __builtin_amdgcn_mfma_f32_16x16x32_bf16(af, bfr[g][0], acc[0], 0, 0, 0);
                acc[1] = __builtin_amdgcn_mfma_f32_16x16x32_bf16(af, bfr[g][1], acc[1], 0, 0, 0);

                // -- substage B: mean_z (plane 2+g) --
                #pragma unroll
                for (int j = 0; j < 8; ++j) {
                    rcp[j] = __builtin_amdgcn_rcpf(cnt[j] + 1e-5f) * INV_QS;
                    const float pay = (float)(zz[j] & 0xFFFFFF);            // exact (<2^24)
                    av[j] = (pay - cnt[j] * PBIASF) * rcp[j];
                }
                #pragma unroll
                for (int j = 0; j < 8; ++j) af[j] = f2bf(av[j]);
                acc[0] = __builtin_amdgcn_mfma_f32_16x16x32_bf16(af, bfr[2 + g][0], acc[0], 0, 0, 0);
                acc[1] = __builtin_amdgcn_mfma_f32_16x16x32_bf16(af, bfr[2 + g][1], acc[1], 0, 0, 0);

                // -- substage C: mean_r (plane 4+g) --
                #pragma unroll
                for (int j = 0; j < 8; ++j)
                    av[j] = ((float)rrw[j] - cnt[j] * PBIASF) * rcp[j];
                #pragma unroll
                for (int j = 0; j < 8; ++j) af[j] = f2bf(av[j]);
                acc[0] = __builtin_amdgcn_mfma_f32_16x16x32_bf16(af, bfr[4 + g][0], acc[0], 0, 0, 0);
                acc[1] = __builtin_amdgcn_mfma_f32_16x16x32_bf16(af, bfr[4 + g][1], acc[1], 0, 0, 0);
            }

            // ---- epilogue: +bias, store x, BN partials. C/D: col=lane&15, row=quad*4+i ----
            #pragma unroll
            for (int tt = 0; tt < 2; ++tt) {
                const int tch = half * 2 + tt;
                const float bias = bvec[tch * 16 + col];
                #pragma unroll
                for (int i = 0; i < 4; ++i) {
                    const int row = gbase + quad * 4 + i;
                    if (row < M) {
                        const float xv = acc[tt][i] + bias;
                        xout[(size_t)row * 64 + tch * 16 + col] = xv;
                        psum[tt] += xv;
                        psq[tt]  += xv * xv;
                    }
                }
            }
        }
    }

    // ---- BN partials: quad-reduce; lanes 0..31 carry this wave's 32 channels ----
    #pragma unroll
    for (int tt = 0; tt < 2; ++tt) {
        psum[tt] += __shfl_xor(psum[tt], 16);
        psum[tt] += __shfl_xor(psum[tt], 32);
        psq[tt]  += __shfl_xor(psq[tt], 16);
        psq[tt]  += __shfl_xor(psq[tt], 32);
    }
    // lane<32: quad in {0,1} selects tt; ch = half*32 + lane = (2*half+tt)*16 + col
    const float myS = (quad & 1) ? psum[1] : psum[0];
    const float myQ = (quad & 1) ? psq[1]  : psq[0];
    if (lane < 32) {
        unsigned long long* dst = totals + (blockIdx.x & (REPS - 1)) * 128 + half * 32 + lane;
        atomicAdd(dst,      (unsigned long long)(long long)(myS * TSC));
        atomicAdd(dst + 64, (unsigned long long)(long long)(myQ * TSC));
    }
}

__global__ __launch_bounds__(256)
void k3_bn_apply(float4* __restrict__ x,
                 const unsigned long long* __restrict__ totals,
                 const float* __restrict__ gamma,
                 const float* __restrict__ beta,
                 float invM, int n4)
{
    __shared__ float sT[128];
    __shared__ float sa[64];
    __shared__ float sc[64];
    const int t = threadIdx.x;
    if (t < 128) {   // sum replicas: deterministic across blocks
        long long s = 0;
        #pragma unroll
        for (int rep = 0; rep < REPS; ++rep) s += (long long)totals[rep * 128 + t];
        sT[t] = (float)s * (invM * INV_TSC);
    }
    __syncthreads();
    if (t < 64) {
        const float mu   = sT[t];
        const float q    = sT[64 + t];
        const float var  = q - mu * mu;
        const float rstd = 1.0f / sqrtf(var + 1e-5f);
        const float a    = gamma[t] * rstd;
        sa[t] = a;
        sc[t] = beta[t] - mu * a;
    }
    __syncthreads();
    const int stride = gridDim.x * 256;
    for (int i = blockIdx.x * 256 + t; i < n4; i += stride) {
        const float4 a = ((const float4*)sa)[i & 15];   // 64 ch = 16 float4
        const float4 c = ((const float4*)sc)[i & 15];
        float4 v = x[i];
        v.x = fmaxf(fmaf(v.x, a.x, c.x), 0.f);
        v.y = fmaxf(fmaf(v.y, a.y, c.y), 0.f);
        v.z = fmaxf(fmaf(v.z, a.z, c.z), 0.f);
        v.w = fmaxf(fmaf(v.w, a.w, c.w), 0.f);
        x[i] = v;
    }
}

extern "C" void kernel_launch(void* const* d_in, const int* in_sizes, int n_in,
                              void* d_out, int out_size, void* d_ws, size_t ws_size,
                              hipStream_t stream) {
    const uint2*  feat2 = (const uint2*)d_in[0];   // [M,64,4] fp32 viewed as uint2 pairs
    const int*    nump  = (const int*)d_in[1];     // [M]
    // d_in[2] = coors (unused)
    const float*  W     = (const float*)d_in[3];   // [64,192]
    const float*  bvec  = (const float*)d_in[4];   // [64]
    const float*  gamma = (const float*)d_in[5];   // [64]
    const float*  beta  = (const float*)d_in[6];   // [64]

    const int M = in_sizes[1];
    float* xout = (float*)d_out;
    short* wsW  = (short*)d_ws;                                   // [24*64*8] bf16 B-fragments
    unsigned long long* totals =
        (unsigned long long*)((char*)d_ws + 24 * 64 * 8 * sizeof(short));  // [REPS*128] u64

    k0_prep<<<16, 256, 0, stream>>>(W, wsW, totals);

    const int nblk = (M + 16 * TILES - 1) / (16 * TILES);   // 64 rows/block, pipelined tiles
    k1_hist_mfma<<<nblk, 128, 0, stream>>>(feat2, nump, (const bf16x8*)wsW, bvec, xout, totals, M);

    const int n4 = out_size / 4;
    const int nblk3 = (n4 + 256 * 16 - 1) / (256 * 16);
    k3_bn_apply<<<nblk3, 256, 0, stream>>>((float4*)d_out, totals, gamma, beta,
                                           1.0f / (float)M, n4);
}